// Round 12
// baseline (118.039 us; speedup 1.0000x reference)
//
#include <hip/hip_runtime.h>
#include <stdint.h>

// BinarizeLinear: out[i][j] = sum_k sign(x[i][k]) * sign(W[j][k]) + bias[j]
// R12: LDS-bandwidth attack. R3/R10/R11 (3 schedules) all hit 83 µs,
// MfmaUtil ~34% -> binding pipe is LDS reads (~54 µs/CU) not MFMA (~35 µs).
// Fix: B never touches LDS. binarize_wt writes wb_t in FRAGMENT-MAJOR layout
// (block (kt=k/64, cb=col/16) = 1024 B: [ksl=(k%64)/16][col%16][16 k-bytes]),
// so a wave's B-frag = global_load_dwordx4 at block_base + lane*16 (perfectly
// coalesced, L2/L3-served: wb_t is 4 MB). LDS carries only A (16 KB dbuf).
// Per-iter: Bx4 loads -> A ds_read x4 -> lgkm(0) -> BAR -> STAGE_A(cur,t+2)
// -> vmcnt(1) [retires B + older t+1 stage, keeps t+2 stage in flight]
// -> MFMA x16 -> BAR [publishes all waves' t+1 stages].
// A-path identical to R11 (verified): BK=64, swizzle slot^((row>>1)&3) on
// stage-source and ds_read. Tile 128x256, 8 waves of 64x64, 2 blocks/CU.
// Exact: +-1 products, int sums <= 2048 -> fp32-exact vs reference.

#define Mdim 16384
#define Ndim 2048
#define Kdim 2048
#define NT 32  // K-tiles of 64 i8 elements

using i32x4 = __attribute__((ext_vector_type(4))) int;

__global__ __launch_bounds__(256) void binarize_x(const float* __restrict__ x,
                                                  int8_t* __restrict__ out, int n16) {
  int i = blockIdx.x * 256 + threadIdx.x;
  if (i >= n16) return;
  const float4* p = (const float4*)x + (size_t)i * 4;
  float4 f0 = p[0], f1 = p[1], f2 = p[2], f3 = p[3];
  float s[16] = {f0.x, f0.y, f0.z, f0.w, f1.x, f1.y, f1.z, f1.w,
                 f2.x, f2.y, f2.z, f2.w, f3.x, f3.y, f3.z, f3.w};
  union { int8_t b[16]; int4 v; } u;
#pragma unroll
  for (int j = 0; j < 16; ++j) u.b[j] = s[j] > 0.0f ? (int8_t)1 : (int8_t)-1;
  ((int4*)out)[i] = u.v;
}

// W -> fragment-major binarized layout.
// Thread i: row j = i>>7, k0 = (i&127)*16. Writes 16 B to
// wb_t[(kt*128 + j/16)*1024 + ksl*256 + (j%16)*16], kt=k0/64, ksl=(k0/16)&3.
__global__ __launch_bounds__(256) void binarize_wt(const float* __restrict__ w,
                                                   int8_t* __restrict__ out, int n16) {
  int i = blockIdx.x * 256 + threadIdx.x;
  if (i >= n16) return;
  const int j = i >> 7;
  const int k0 = (i & 127) << 4;
  const float4* p = (const float4*)(w + (size_t)j * Kdim + k0);
  float4 f0 = p[0], f1 = p[1], f2 = p[2], f3 = p[3];
  float s[16] = {f0.x, f0.y, f0.z, f0.w, f1.x, f1.y, f1.z, f1.w,
                 f2.x, f2.y, f2.z, f2.w, f3.x, f3.y, f3.z, f3.w};
  union { int8_t b[16]; int4 v; } u;
#pragma unroll
  for (int jj = 0; jj < 16; ++jj) u.b[jj] = s[jj] > 0.0f ? (int8_t)1 : (int8_t)-1;
  const int kt = k0 >> 6;
  const int ksl = (k0 >> 4) & 3;
  const size_t dst = ((size_t)(kt * 128 + (j >> 4)) << 10) + (ksl << 8) + ((j & 15) << 4);
  *(int4*)(out + dst) = u.v;
}

__device__ __forceinline__ void gl_lds16(const void* gsrc, void* ldst) {
  __builtin_amdgcn_global_load_lds(
      (const __attribute__((address_space(1))) void*)gsrc,
      (__attribute__((address_space(3))) void*)ldst, 16, 0, 0);
}

__global__ __launch_bounds__(512, 4) void bin_gemm_i8_breg(const int8_t* __restrict__ A,
                                                           const int8_t* __restrict__ WT,
                                                           const float* __restrict__ bias,
                                                           float* __restrict__ C) {
  // A only: [2][128 rows][64 B] = 16 KB.
  __shared__ __align__(16) int8_t As[2][128 * 64];

  const int tid = threadIdx.x;
  const int lane = tid & 63;
  const int wid = tid >> 6;  // 0..7
  const int wm = wid >> 2;   // 0..1 (M half: 64 rows)
  const int wn = wid & 3;    // 0..3 (N quarter: 64 cols)

  // XCD swizzle: 1024 blocks, %8==0 -> bijective. Within an XCD, 8 consecutive
  // q share one brow-panel (A L2-reuse); all 8 bcols covered (wb_t hot).
  const int bid = blockIdx.x;
  const int swz = (bid & 7) * 128 + (bid >> 3);
  const long brow = (long)(swz >> 3) * 128;  // 128 M-panels
  const int bcol16 = (swz & 7) * 16;         // col-tile base in units of 16 cols

  // ---- A staging: linear LDS dest; swizzle on global SOURCE slot (R11) ----
  const int slin = lane & 3;
  const int sgcol = (slin ^ ((lane >> 3) & 3)) * 16;
  const int srA = wid * 16 + (lane >> 2);  // 1 gl_lds/wave covers 16 rows

  // ---- A fragment ds_read offsets (swizzled: slot ^ ((row>>1)&3)) ----
  int offA[4];
#pragma unroll
  for (int fr = 0; fr < 4; ++fr) {
    const int ra = wm * 64 + fr * 16 + (lane & 15);
    const int s = lane >> 4;
    offA[fr] = ra * 64 + ((s ^ ((ra >> 1) & 3)) * 16);
  }

  // ---- B fragment global base: fragment (kt, cb = bcol16 + wn*4 + fc) ----
  // addr = WT + (kt*128 + cb)*1024 + lane*16; per-iter stride 128*1024.
  const int8_t* wtBase = WT + ((size_t)(bcol16 + wn * 4) << 10) + (lane << 4);

  i32x4 acc[4][4] = {};  // 64 regs (AGPR)
  i32x4 a[4], b[4];

#define BAR() asm volatile("s_barrier" ::: "memory")
#define STAGE_A(BUF, KT)                                                            \
  do {                                                                              \
    const int8_t* sa_ = A + (brow + srA) * (long)Kdim + ((long)(KT) << 6) + sgcol;  \
    gl_lds16(sa_, &As[BUF][wid * 1024]);                                            \
  } while (0)

  // ---- prologue: stage A tiles 0,1; tile0 resident (1 newer outstanding).
  STAGE_A(0, 0);
  STAGE_A(1, 1);
  asm volatile("s_waitcnt vmcnt(1)" ::: "memory");
  BAR();

#pragma unroll 1
  for (int t = 0; t < NT; ++t) {
    const int cur = t & 1;

    // B-frag loads for tile t (oldest VMEM this iter; retire at vmcnt below)
    const int8_t* wt = wtBase + ((size_t)t << 17);  // t*128*1024
#pragma unroll
    for (int fc = 0; fc < 4; ++fc) b[fc] = *(const i32x4*)(wt + (fc << 10));

    // A reads of buf cur, drained before the barrier
#pragma unroll
    for (int fr = 0; fr < 4; ++fr) a[fr] = *(const i32x4*)&As[cur][offA[fr]];
    asm volatile("s_waitcnt lgkmcnt(0)" ::: "memory");
    BAR();  // all waves done reading As[cur]

    // overwrite cur with tile t+2 (post-barrier: safe)
    if (t + 2 < NT) {
      STAGE_A(cur, t + 2);
      // retire B loads + last iter's t+1 stage; keep the fresh t+2 stage in flight
      asm volatile("s_waitcnt vmcnt(1)" ::: "memory");
    } else {
      asm volatile("s_waitcnt vmcnt(0)" ::: "memory");
    }

    __builtin_amdgcn_s_setprio(1);
#pragma unroll
    for (int fr = 0; fr < 4; ++fr)
#pragma unroll
      for (int fc = 0; fc < 4; ++fc)
        acc[fr][fc] = __builtin_amdgcn_mfma_i32_16x16x64_i8(a[fr], b[fc], acc[fr][fc], 0, 0, 0);
    __builtin_amdgcn_s_setprio(0);
    BAR();  // all waves past vmcnt -> t+1 stages published for next iter's reads
  }

  // ---- epilogue: C/D layout col=lane&15, row=(lane>>4)*4+reg ----
#pragma unroll
  for (int fc = 0; fc < 4; ++fc) {
    const long col = (long)(bcol16 + wn * 4 + fc) * 16 + (lane & 15);
    const float bj = bias[col];
#pragma unroll
    for (int fr = 0; fr < 4; ++fr) {
      const long row0 = brow + wm * 64 + fr * 16 + (lane >> 4) * 4;
#pragma unroll
      for (int r = 0; r < 4; ++r) {
        C[(row0 + r) * (long)Ndim + col] = (float)acc[fr][fc][r] + bj;
      }
    }
  }
#undef BAR
#undef STAGE_A
}

extern "C" void kernel_launch(void* const* d_in, const int* in_sizes, int n_in,
                              void* d_out, int out_size, void* d_ws, size_t ws_size,
                              hipStream_t stream) {
  const float* x = (const float*)d_in[0];
  const float* w = (const float*)d_in[1];
  const float* bias = (const float*)d_in[2];
  float* out = (float*)d_out;

  int8_t* xb = (int8_t*)d_ws;               // 33.5 MB, row-major
  int8_t* wbt = xb + (size_t)Mdim * Kdim;   // + 4.2 MB, fragment-major

  const int nx16 = Mdim * Kdim / 16;  // 2097152
  const int nw16 = Ndim * Kdim / 16;  // 262144
  binarize_x<<<nx16 / 256, 256, 0, stream>>>(x, xb, nx16);
  binarize_wt<<<nw16 / 256, 256, 0, stream>>>(w, wbt, nw16);

  dim3 grid((Mdim / 128) * (Ndim / 256));  // 1024 blocks, %8==0
  bin_gemm_i8_breg<<<grid, 512, 0, stream>>>(xb, wbt, bias, out);
}

// Round 13
// 82.636 us; speedup vs baseline: 1.4284x; 1.4284x over previous
//
#include <hip/hip_runtime.h>
#include <stdint.h>

// BinarizeLinear: out[i][j] = sum_k sign(x[i][k]) * sign(W[j][k]) + bias[j]
// R13: dtype jump to MX-FP4. Four schedule variants (R3/R10/R11/R12) all hit
// 83 +- 1 µs, MfmaUtil ~34% -> not schedule-bound; aggregate byte-movement +
// i8 MFMA floor (35 µs) is. Binarized +-1 is exact in fp4 e2m1 (+1=0x2,
// -1=0xA); mfma_scale_f32_16x16x128_f8f6f4 with E8M0 scale 0x7F (=1.0)
// accumulates in f32 -> integer sums <= 2048 stay bit-exact.
// Halves: fragment bytes (K=128 per 16B/lane), staging, xb (16.8 MB),
// wb (2.1 MB), binarize writes. MFMA floor 35 -> 19 µs (7228 TOPS, m25).
// Layout safety: A-rows and B-cols packed with the SAME k-order -> any HW
// k-permutation cancels in the dot product; row/col = lane&15; C/D layout
// shape-determined (m127/m128).
// GEMM structure = R11 verified: tile 128x256, BK=64B rows, 8 waves 64x64,
// swizzle slot^((row>>1)&3) on stage-source + ds_read, STAGE post-BAR,
// vmcnt(3) counted prefetch. 1 block/CU (reg ~170 with v8 temps).

#define Mdim 16384
#define Ndim 2048
#define Kdim 2048
#define NT 16  // K-tiles of 128 fp4 (64 B)

using i32x4 = __attribute__((ext_vector_type(4))) int;
using i32x8 = __attribute__((ext_vector_type(8))) int;
using f32x4 = __attribute__((ext_vector_type(4))) float;

// Binarize f32 -> packed fp4 (+1=0x2, -1=0xA), 16 f32 -> 8 bytes per thread.
__global__ __launch_bounds__(256) void binarize_fp4(const float* __restrict__ x,
                                                    const float* __restrict__ w,
                                                    uint8_t* __restrict__ out,
                                                    int nx16, int ntot16) {
  int i = blockIdx.x * 256 + threadIdx.x;
  if (i >= ntot16) return;
  const float4* p = (i < nx16) ? ((const float4*)x + (size_t)i * 4)
                               : ((const float4*)w + (size_t)(i - nx16) * 4);
  float4 f0 = p[0], f1 = p[1], f2 = p[2], f3 = p[3];
  float s[16] = {f0.x, f0.y, f0.z, f0.w, f1.x, f1.y, f1.z, f1.w,
                 f2.x, f2.y, f2.z, f2.w, f3.x, f3.y, f3.z, f3.w};
  union { uint8_t b[8]; uint2 v; } u;
#pragma unroll
  for (int j = 0; j < 8; ++j) {
    const unsigned lo = s[2 * j] > 0.0f ? 0x2u : 0xAu;
    const unsigned hi = s[2 * j + 1] > 0.0f ? 0x2u : 0xAu;
    u.b[j] = (uint8_t)(lo | (hi << 4));
  }
  ((uint2*)out)[i] = u.v;  // xb4 then wb4, contiguous
}

__device__ __forceinline__ void gl_lds16(const void* gsrc, void* ldst) {
  __builtin_amdgcn_global_load_lds(
      (const __attribute__((address_space(1))) void*)gsrc,
      (__attribute__((address_space(3))) void*)ldst, 16, 0, 0);
}

__device__ __forceinline__ i32x8 dup8(i32x4 v) {
  i32x8 r;
  r[0] = v[0]; r[1] = v[1]; r[2] = v[2]; r[3] = v[3];
  r[4] = v[0]; r[5] = v[1]; r[6] = v[2]; r[7] = v[3];  // fp4 uses regs [0:3]
  return r;
}

__global__ __launch_bounds__(512, 1) void bin_gemm_fp4(const uint8_t* __restrict__ A4,
                                                       const uint8_t* __restrict__ W4,
                                                       const float* __restrict__ bias,
                                                       float* __restrict__ C) {
  // Row = 64 B = 128 fp4 of one K-tile. A: [2][128 rows], B: [2][256 rows]. 48 KB.
  __shared__ __align__(16) uint8_t As[2][128 * 64];
  __shared__ __align__(16) uint8_t Bs[2][256 * 64];

  const int tid = threadIdx.x;
  const int lane = tid & 63;
  const int wid = tid >> 6;  // 0..7
  const int wm = wid >> 2;   // 0..1 (M half: 64 rows)
  const int wn = wid & 3;    // 0..3 (N quarter: 64 cols)

  // XCD swizzle: 1024 blocks, %8==0 -> bijective; consecutive j per XCD sweep
  // bcol fastest -> the 8 A-panel sharers are co-XCD (L2 reuse).
  const int bid = blockIdx.x;
  const int swz = (bid & 7) * 128 + (bid >> 3);
  const long brow = (long)(swz >> 3) * 128;  // 128 M-panels
  const long bcol = (long)(swz & 7) * 256;   // 8 col-tiles

  // ---- staging: linear LDS dest; swizzle on global SOURCE slot (R11) ----
  const int slin = lane & 3;
  const int sgcol = (slin ^ ((lane >> 3) & 3)) * 16;
  const int srA = wid * 16 + (lane >> 2);  // A rows, 1 gl_lds/wave = 16 rows
  const int srB = wid * 32 + (lane >> 2);  // B rows, 2 gl_lds/wave

  // ---- fragment ds_read offsets (swizzled: slot ^ ((row>>1)&3)) ----
  int offA[4], offB[4];
#pragma unroll
  for (int fr = 0; fr < 4; ++fr) {
    const int ra = wm * 64 + fr * 16 + (lane & 15);
    const int s = lane >> 4;
    offA[fr] = ra * 64 + ((s ^ ((ra >> 1) & 3)) * 16);
  }
#pragma unroll
  for (int fc = 0; fc < 4; ++fc) {
    const int rb = wn * 64 + fc * 16 + (lane & 15);
    const int s = lane >> 4;
    offB[fc] = rb * 64 + ((s ^ ((rb >> 1) & 3)) * 16);
  }

  f32x4 acc[4][4] = {};  // f32 accumulators (exact for int sums <= 2048)
  i32x4 a[4], b[4];

  const long rowBytes = Kdim / 2;  // 1024 B per logical row

#define BAR() asm volatile("s_barrier" ::: "memory")
#define STAGE(BUF, KT)                                                                  \
  do {                                                                                  \
    const uint8_t* sa_ = A4 + (brow + srA) * rowBytes + ((long)(KT) << 6) + sgcol;      \
    gl_lds16(sa_, &As[BUF][wid * 1024]);                                                \
    const uint8_t* sb_ = W4 + (bcol + srB) * rowBytes + ((long)(KT) << 6) + sgcol;      \
    gl_lds16(sb_, &Bs[BUF][wid * 2048]);                                                \
    gl_lds16(sb_ + 16 * rowBytes, &Bs[BUF][wid * 2048 + 1024]);                         \
  } while (0)

  // ---- prologue: stage tiles 0,1 (3 gl_lds/wave each); tile0 resident.
  STAGE(0, 0);
  STAGE(1, 1);
  asm volatile("s_waitcnt vmcnt(3)" ::: "memory");
  BAR();

#pragma unroll 1
  for (int t = 0; t < NT; ++t) {
    const int cur = t & 1;

    // reads of buf cur (8 x ds_read_b128), drained before the barrier
#pragma unroll
    for (int fr = 0; fr < 4; ++fr) a[fr] = *(const i32x4*)&As[cur][offA[fr]];
#pragma unroll
    for (int fc = 0; fc < 4; ++fc) b[fc] = *(const i32x4*)&Bs[cur][offB[fc]];
    asm volatile("s_waitcnt lgkmcnt(0)" ::: "memory");
    BAR();  // all waves done reading buf cur

    // overwrite cur with tile t+2 (post-barrier: safe)
    if (t + 2 < NT) STAGE(cur, t + 2);

    __builtin_amdgcn_s_setprio(1);
#pragma unroll
    for (int fr = 0; fr < 4; ++fr) {
      const i32x8 a8 = dup8(a[fr]);
#pragma unroll
      for (int fc = 0; fc < 4; ++fc) {
        const i32x8 b8 = dup8(b[fc]);
        // cbsz=4 (A=fp4), blgp=4 (B=fp4); scales E8M0 0x7F = 1.0, opsel 0.
        acc[fr][fc] = __builtin_amdgcn_mfma_scale_f32_16x16x128_f8f6f4(
            a8, b8, acc[fr][fc], 4, 4, 0, 0x7F7F7F7F, 0, 0x7F7F7F7F);
      }
    }
    __builtin_amdgcn_s_setprio(0);

    // retire tile t+1's stages (3 newest = tile t+2's, just issued)
    if (t < NT - 2) {
      asm volatile("s_waitcnt vmcnt(3)" ::: "memory");
    } else {
      asm volatile("s_waitcnt vmcnt(0)" ::: "memory");
    }
    BAR();
  }

  // ---- epilogue: C/D layout col=lane&15, row=(lane>>4)*4+reg ----
#pragma unroll
  for (int fc = 0; fc < 4; ++fc) {
    const long col = bcol + wn * 64 + fc * 16 + (lane & 15);
    const float bj = bias[col];
#pragma unroll
    for (int fr = 0; fr < 4; ++fr) {
      const long row0 = brow + wm * 64 + fr * 16 + (lane >> 4) * 4;
#pragma unroll
      for (int r = 0; r < 4; ++r) {
        C[(row0 + r) * (long)Ndim + col] = acc[fr][fc][r] + bj;
      }
    }
  }
#undef BAR
#undef STAGE
}

extern "C" void kernel_launch(void* const* d_in, const int* in_sizes, int n_in,
                              void* d_out, int out_size, void* d_ws, size_t ws_size,
                              hipStream_t stream) {
  const float* x = (const float*)d_in[0];
  const float* w = (const float*)d_in[1];
  const float* bias = (const float*)d_in[2];
  float* out = (float*)d_out;

  uint8_t* xb4 = (uint8_t*)d_ws;                 // 16.8 MB (fp4-packed)
  uint8_t* wb4 = xb4 + (size_t)Mdim * Kdim / 2;  // + 2.1 MB (ws >= 18.9 MB)

  const int nx16 = Mdim * Kdim / 16;  // 16-f32 units
  const int nw16 = Ndim * Kdim / 16;
  const int ntot16 = nx16 + nw16;
  binarize_fp4<<<(ntot16 + 255) / 256, 256, 0, stream>>>(x, w, xb4, nx16, ntot16);

  dim3 grid((Mdim / 128) * (Ndim / 256));  // 1024 blocks, %8==0
  bin_gemm_fp4<<<grid, 512, 0, stream>>>(xb4, wb4, bias, out);
}